// Round 7
// baseline (419.336 us; speedup 1.0000x reference)
//
#include <hip/hip_runtime.h>
#include <math.h>

#define N_NODES 100000
#define N_EDGES 3200000
#define NBLK_EDGE ((N_EDGES + 255) / 256)
#define NBLK_NODE ((N_NODES + 255) / 256)

#define NB 64                                // nodes per bucket
#define NBUCK ((N_NODES + NB - 1) / NB)      // 1563
#define NSLICE 256
#define SLICE (N_EDGES / NSLICE)             // 12500 exact
#define P2 2048                              // pow2 >= NBUCK for the scan

typedef _Float16 h2f16 __attribute__((ext_vector_type(2)));
typedef __fp16 f16x8 __attribute__((ext_vector_type(8)));   // MFMA operand type
typedef float f32x4 __attribute__((ext_vector_type(4)));
typedef unsigned u32x4 __attribute__((ext_vector_type(4)));

// packed-weight table offsets (h2f16 units)
#define PK_ENC_A2 0     // 2 tiles x 64 lanes x 4 pairs (W2^T A-fragments)
#define PK_DEC_A2 512
#define PK_ENC_W1 1024  // [q][j][kp] 4*8*4
#define PK_DEC_W1 1152  // [q][j][kp] 4*8*2
#define PK_ENC_H 1216   // [q][r][head] pairs (out 4q+r, 16+4q+r)
#define PK_DEC_H 1280
#define PK_TOTAL 1344

__device__ __forceinline__ h2f16 mkh2(float a, float b) {
  h2f16 h;
  h.x = (_Float16)a;
  h.y = (_Float16)b;
  return h;
}
__device__ __forceinline__ float fdot2(h2f16 a, h2f16 b, float c) {
  return __builtin_amdgcn_fdot2(a, b, c, false);
}
__device__ __forceinline__ h2f16 pk(float a, float b) {
  auto r = __builtin_amdgcn_cvt_pkrtz(a, b);  // v_cvt_pkrtz_f16_f32
  return __builtin_bit_cast(h2f16, r);
}
__device__ __forceinline__ unsigned h2u(h2f16 h) {
  return __builtin_bit_cast(unsigned, h);
}
__device__ __forceinline__ f32x4 mfma16(f16x8 a, f16x8 b, f32x4 c) {
  return __builtin_amdgcn_mfma_f32_16x16x32_f16(a, b, c, 0, 0, 0);
}

// ---------------- pack weights into MFMA-fragment-ready tables ----------------
__global__ __launch_bounds__(256) void pack_weights(
    const float* __restrict__ eW1, const float* __restrict__ eW2,
    const float* __restrict__ mW, const float* __restrict__ vW,
    const float* __restrict__ dW1, const float* __restrict__ dW2,
    const float* __restrict__ dW3, h2f16* __restrict__ wpk) {
  int t = threadIdx.x;
  // A-fragments of W2^T: a[j] = W2[k=q*8+j][out=16*tile+c], pairs over j
  for (int i = t; i < 512; i += 256) {
    int tl = i >> 8, rest = i & 255, lane = rest >> 2, p = rest & 3;
    int q = lane >> 4, c = lane & 15;
    int k0 = q * 8 + 2 * p, out = 16 * tl + c;
    wpk[PK_ENC_A2 + i] = mkh2(eW2[k0 * 32 + out], eW2[(k0 + 1) * 32 + out]);
    wpk[PK_DEC_A2 + i] = mkh2(dW2[k0 * 32 + out], dW2[(k0 + 1) * 32 + out]);
  }
  for (int i = t; i < 128; i += 256) {  // enc W1 cols for outputs q*8+j, K=8
    int q = i >> 5, j = (i >> 2) & 7, kp = i & 3;
    wpk[PK_ENC_W1 + i] =
        mkh2(eW1[(2 * kp) * 32 + q * 8 + j], eW1[(2 * kp + 1) * 32 + q * 8 + j]);
  }
  for (int i = t; i < 64; i += 256) {  // dec W1, K=4
    int q = i >> 4, j = (i >> 1) & 7, kp = i & 1;
    wpk[PK_DEC_W1 + i] =
        mkh2(dW1[(2 * kp) * 32 + q * 8 + j], dW1[(2 * kp + 1) * 32 + q * 8 + j]);
  }
  for (int i = t; i < 64; i += 256) {  // head pairs over (out0=4q+r, out1=16+4q+r)
    int q = i >> 4, r = (i >> 2) & 3, h = i & 3;
    int o0 = 4 * q + r, o1 = 16 + 4 * q + r;
    float w0 = (h < 2) ? mW[o0 * 2 + h] : vW[o0 * 2 + (h - 2)];
    float w1 = (h < 2) ? mW[o1 * 2 + h] : vW[o1 * 2 + (h - 2)];
    wpk[PK_ENC_H + i] = mkh2(w0, w1);
    wpk[PK_DEC_H + i] = mkh2(dW3[o0 * 4 + h], dW3[o1 * 4 + h]);
  }
}

// ---------------- BatchNorm statistics ----------------
__global__ void bn_reduce(const float4* __restrict__ x, float* __restrict__ bns) {
  float s0 = 0, s1 = 0, s2 = 0, s3 = 0, q0 = 0, q1 = 0, q2 = 0, q3 = 0;
  for (int i = blockIdx.x * blockDim.x + threadIdx.x; i < N_NODES;
       i += gridDim.x * blockDim.x) {
    float4 v = x[i];
    s0 += v.x; s1 += v.y; s2 += v.z; s3 += v.w;
    q0 += v.x * v.x; q1 += v.y * v.y; q2 += v.z * v.z; q3 += v.w * v.w;
  }
#pragma unroll
  for (int o = 32; o; o >>= 1) {
    s0 += __shfl_down(s0, o); s1 += __shfl_down(s1, o);
    s2 += __shfl_down(s2, o); s3 += __shfl_down(s3, o);
    q0 += __shfl_down(q0, o); q1 += __shfl_down(q1, o);
    q2 += __shfl_down(q2, o); q3 += __shfl_down(q3, o);
  }
  __shared__ float red[4][8];
  int w = threadIdx.x >> 6;
  if ((threadIdx.x & 63) == 0) {
    red[w][0] = s0; red[w][1] = s1; red[w][2] = s2; red[w][3] = s3;
    red[w][4] = q0; red[w][5] = q1; red[w][6] = q2; red[w][7] = q3;
  }
  __syncthreads();
  if (threadIdx.x < 8) {
    float acc = red[0][threadIdx.x] + red[1][threadIdx.x] +
                red[2][threadIdx.x] + red[3][threadIdx.x];
    atomicAdd(&bns[threadIdx.x], acc);
  }
}

__global__ void bn_final(const float* __restrict__ bns,
                         const float* __restrict__ gamma,
                         const float* __restrict__ beta,
                         float* __restrict__ ab) {
  int d = threadIdx.x;
  if (d < 4) {
    float mean = bns[d] * (1.0f / N_NODES);
    float var = bns[4 + d] * (1.0f / N_NODES) - mean * mean;
    float a = gamma[d] * rsqrtf(var + 1e-5f);
    ab[d] = a;
    ab[4 + d] = beta[d] - mean * a;  // xn = a*x + b
  }
}

// ---------------- counting sort by target bucket (no global atomics) -------
__global__ __launch_bounds__(256) void edge_hist(const int* __restrict__ tgt,
                                                 unsigned* __restrict__ hist) {
  __shared__ unsigned h[NBUCK];
  for (int i = threadIdx.x; i < NBUCK; i += 256) h[i] = 0;
  __syncthreads();
  int e0 = blockIdx.x * SLICE;
  for (int i = threadIdx.x; i < SLICE; i += 256)
    atomicAdd(&h[((unsigned)tgt[e0 + i]) >> 6], 1u);
  __syncthreads();
  for (int i = threadIdx.x; i < NBUCK; i += 256)
    hist[(size_t)blockIdx.x * NBUCK + i] = h[i];
}

__global__ __launch_bounds__(256) void bucket_tot(const unsigned* __restrict__ hist,
                                                  unsigned* __restrict__ tot) {
  int k = blockIdx.x * 256 + threadIdx.x;
  if (k >= NBUCK) return;
  unsigned s = 0;
#pragma unroll 8
  for (int b = 0; b < NSLICE; ++b) s += hist[(size_t)b * NBUCK + k];
  tot[k] = s;
}

__global__ __launch_bounds__(1024) void bucket_start(const unsigned* __restrict__ tot,
                                                     unsigned* __restrict__ start) {
  __shared__ unsigned sa[P2], sb[P2];
  for (int k = threadIdx.x; k < P2; k += 1024)
    sa[k] = (k < NBUCK) ? tot[k] : 0u;
  __syncthreads();
  unsigned *srcp = sa, *dstp = sb;
  for (int off = 1; off < P2; off <<= 1) {
    for (int k = threadIdx.x; k < P2; k += 1024)
      dstp[k] = srcp[k] + (k >= off ? srcp[k - off] : 0u);
    __syncthreads();
    unsigned* t = srcp; srcp = dstp; dstp = t;
  }
  for (int k = threadIdx.x; k <= NBUCK; k += 1024)
    start[k] = (k == 0) ? 0u : srcp[k - 1];
}

__global__ __launch_bounds__(256) void bucket_bases(unsigned* __restrict__ hist,
                                                    const unsigned* __restrict__ start) {
  int wv = threadIdx.x >> 6, lane = threadIdx.x & 63;
  int k = blockIdx.x * 4 + wv;
  if (k >= NBUCK) return;
  unsigned v0 = hist[(size_t)(4 * lane + 0) * NBUCK + k];
  unsigned v1 = hist[(size_t)(4 * lane + 1) * NBUCK + k];
  unsigned v2 = hist[(size_t)(4 * lane + 2) * NBUCK + k];
  unsigned v3 = hist[(size_t)(4 * lane + 3) * NBUCK + k];
  unsigned p1 = v0, p2 = v0 + v1, p3 = v0 + v1 + v2;
  unsigned s = p3 + v3;
  unsigned incl = s;
#pragma unroll
  for (int off = 1; off < 64; off <<= 1) {
    unsigned t = __shfl_up(incl, off);
    incl += (lane >= off) ? t : 0u;
  }
  unsigned base = start[k] + (incl - s);
  hist[(size_t)(4 * lane + 0) * NBUCK + k] = base;
  hist[(size_t)(4 * lane + 1) * NBUCK + k] = base + p1;
  hist[(size_t)(4 * lane + 2) * NBUCK + k] = base + p2;
  hist[(size_t)(4 * lane + 3) * NBUCK + k] = base + p3;
}

__global__ __launch_bounds__(256) void edge_place(
    const int* __restrict__ src, const int* __restrict__ tgt,
    const unsigned* __restrict__ hist, const unsigned* __restrict__ start,
    unsigned* __restrict__ payload) {
  __shared__ unsigned stage[SLICE];
  __shared__ unsigned offA[NBUCK];
  __shared__ unsigned A2[NBUCK];
  int s = blockIdx.x, tid = threadIdx.x;
  for (int k = tid; k < NBUCK; k += 256) {
    unsigned gb = hist[(size_t)s * NBUCK + k];
    unsigned nb = (s == NSLICE - 1) ? start[k + 1]
                                    : hist[(size_t)(s + 1) * NBUCK + k];
    offA[k] = gb;
    A2[k] = nb - gb;
  }
  __syncthreads();
  for (int d = 1; d < NBUCK; d <<= 1) {
    unsigned tmp[7];
    int m = 0;
    for (int k = tid; k < NBUCK; k += 256, ++m)
      tmp[m] = (k >= d) ? A2[k - d] : 0u;
    __syncthreads();
    m = 0;
    for (int k = tid; k < NBUCK; k += 256, ++m) A2[k] += tmp[m];
    __syncthreads();
  }
  {
    unsigned tmp[7];
    int m = 0;
    for (int k = tid; k < NBUCK; k += 256, ++m)
      tmp[m] = (k == 0) ? 0u : A2[k - 1];
    __syncthreads();
    m = 0;
    for (int k = tid; k < NBUCK; k += 256, ++m) {
      offA[k] -= tmp[m];
      A2[k] = tmp[m];
    }
    __syncthreads();
  }
  int e0 = s * SLICE;
  for (int i = tid; i < SLICE; i += 256) {
    unsigned t = (unsigned)tgt[e0 + i];
    unsigned sr = (unsigned)src[e0 + i];
    unsigned b = t >> 6;
    unsigned lp = atomicAdd(&A2[b], 1u);
    stage[lp] = sr | ((t & 63u) << 17);
  }
  __syncthreads();
  for (int b = tid; b < NBUCK; b += 256) {
    unsigned beg = (b == 0) ? 0u : A2[b - 1];
    unsigned end = A2[b];
    unsigned go = offA[b];
    for (unsigned i = beg; i < end; ++i) payload[go + i] = stage[i];
  }
}

// ---------------- Encoder EdgeConv via MFMA (edges=N cols, outputs=M rows) --
__global__ __launch_bounds__(256) void enc_bucket(
    const float4* __restrict__ x, const unsigned* __restrict__ payload,
    const unsigned* __restrict__ start, const float* __restrict__ ab,
    const float* __restrict__ eb1, const float* __restrict__ eb2,
    const h2f16* __restrict__ wpk, float2* __restrict__ msum,
    float2* __restrict__ vsum, float* __restrict__ cnt) {
  __shared__ float aM0[NB], aM1[NB], aV0[NB], aV1[NB], aC[NB];
  __shared__ float4 xt[NB];
  int k = blockIdx.x, node0 = k * NB;
  int tid = threadIdx.x, w = tid >> 6, lane = tid & 63;
  int q = lane >> 4, c = lane & 15;
  if (tid < NB) {
    int n = node0 + tid;
    aM0[tid] = 0; aM1[tid] = 0; aV0[tid] = 0; aV1[tid] = 0; aC[tid] = 0;
    xt[tid] = x[n < N_NODES ? n : 0];
  }
  __syncthreads();
  float a0 = ab[0], a1 = ab[1], a2 = ab[2], a3 = ab[3];
  float b0 = ab[4], b1 = ab[5], b2 = ab[6], b3 = ab[7];
  // resident weights: W2^T A-fragments (layer2 never touches memory again)
  const u32x4* a2b = (const u32x4*)(wpk + PK_ENC_A2);
  f16x8 A0 = __builtin_bit_cast(f16x8, a2b[lane]);
  f16x8 A1 = __builtin_bit_cast(f16x8, a2b[64 + lane]);
  h2f16 w1e[32];
#pragma unroll
  for (int i = 0; i < 32; ++i) w1e[i] = wpk[PK_ENC_W1 + q * 32 + i];
  h2f16 hw[16];
#pragma unroll
  for (int i = 0; i < 16; ++i) hw[i] = wpk[PK_ENC_H + q * 16 + i];
  float eb1v[8];
#pragma unroll
  for (int j = 0; j < 8; ++j) eb1v[j] = eb1[q * 8 + j];
  float e2a[4], e2b[4];
#pragma unroll
  for (int r = 0; r < 4; ++r) {
    e2a[r] = eb2[4 * q + r];
    e2b[r] = eb2[16 + 4 * q + r];
  }
  unsigned s0 = start[k], e1 = start[k + 1];
  for (unsigned ebase = s0 + (unsigned)w * 16; ebase < e1; ebase += 64) {
    unsigned e = ebase + (unsigned)c;
    unsigned pe = (e < e1) ? e : (e1 - 1);
    unsigned p = payload[pe];
    int si = (int)(p & 0x1FFFFu);
    si = (si < N_NODES) ? si : 0;
    int lti = (int)(p >> 17);
    float4 xj = x[si];
    float4 xi = xt[lti];
    h2f16 f0 = pk(fmaf(a0, xi.x, b0), fmaf(a1, xi.y, b1));
    h2f16 f1 = pk(fmaf(a2, xi.z, b2), fmaf(a3, xi.w, b3));
    h2f16 f2 = pk(a0 * (xj.x - xi.x), a1 * (xj.y - xi.y));
    h2f16 f3 = pk(a2 * (xj.z - xi.z), a3 * (xj.w - xi.w));
    // layer1 in B-fragment layout: lane computes outputs k=q*8+j of its edge
    float r[8];
#pragma unroll
    for (int j = 0; j < 8; ++j) {
      float u = eb1v[j];
      u = fdot2(f0, w1e[4 * j + 0], u);
      u = fdot2(f1, w1e[4 * j + 1], u);
      u = fdot2(f2, w1e[4 * j + 2], u);
      u = fdot2(f3, w1e[4 * j + 3], u);
      r[j] = fmaxf(u, 0.0f);
    }
    u32x4 bu;
    bu[0] = h2u(pk(r[0], r[1]));
    bu[1] = h2u(pk(r[2], r[3]));
    bu[2] = h2u(pk(r[4], r[5]));
    bu[3] = h2u(pk(r[6], r[7]));
    f16x8 B = __builtin_bit_cast(f16x8, bu);
    f32x4 C0 = {0.f, 0.f, 0.f, 0.f}, C1 = {0.f, 0.f, 0.f, 0.f};
    C0 = mfma16(A0, B, C0);  // outputs 0..15  x edges
    C1 = mfma16(A1, B, C1);  // outputs 16..31 x edges
    // heads: lane holds rows {4q+r, 16+4q+r} of its edge column
    float m0 = 0, m1 = 0, v0 = 0, v1 = 0;
#pragma unroll
    for (int rr = 0; rr < 4; ++rr) {
      float d0 = fmaxf(C0[rr] + e2a[rr], 0.0f);
      float d1 = fmaxf(C1[rr] + e2b[rr], 0.0f);
      h2f16 hh = pk(d0, d1);
      m0 = fdot2(hh, hw[4 * rr + 0], m0);
      m1 = fdot2(hh, hw[4 * rr + 1], m1);
      v0 = fdot2(hh, hw[4 * rr + 2], v0);
      v1 = fdot2(hh, hw[4 * rr + 3], v1);
    }
    m0 += __shfl_xor(m0, 16); m0 += __shfl_xor(m0, 32);
    m1 += __shfl_xor(m1, 16); m1 += __shfl_xor(m1, 32);
    v0 += __shfl_xor(v0, 16); v0 += __shfl_xor(v0, 32);
    v1 += __shfl_xor(v1, 16); v1 += __shfl_xor(v1, 32);
    if (lane < 16 && e < e1) {
      atomicAdd(&aM0[lti], m0);
      atomicAdd(&aM1[lti], m1);
      atomicAdd(&aV0[lti], v0);
      atomicAdd(&aV1[lti], v1);
      atomicAdd(&aC[lti], 1.0f);
    }
  }
  __syncthreads();
  if (tid < NB) {
    int n = node0 + tid;
    if (n < N_NODES) {
      msum[n] = make_float2(aM0[tid], aM1[tid]);
      vsum[n] = make_float2(aV0[tid], aV1[tid]);
      cnt[n] = aC[tid];
    }
  }
}

// ---------------- mean + bias + reparameterize ----------------
__global__ __launch_bounds__(256) void node_mid(
    float* __restrict__ msum, float* __restrict__ vsum,
    const float* __restrict__ cnt, const float* __restrict__ eps2,
    const float* __restrict__ mb, const float* __restrict__ vb,
    float* __restrict__ z) {
  int n = blockIdx.x * 256 + threadIdx.x;
  if (n >= N_NODES) return;
  float inv = 1.0f / fmaxf(cnt[n], 1.0f);
  float mu0 = fmaf(msum[2 * n + 0], inv, mb[0]);
  float mu1 = fmaf(msum[2 * n + 1], inv, mb[1]);
  float lv0 = fmaf(vsum[2 * n + 0], inv, vb[0]);
  float lv1 = fmaf(vsum[2 * n + 1], inv, vb[1]);
  msum[2 * n + 0] = mu0;
  msum[2 * n + 1] = mu1;
  vsum[2 * n + 0] = lv0;
  vsum[2 * n + 1] = lv1;
  z[2 * n + 0] = fmaf(eps2[2 * n + 0], expf(0.5f * lv0), mu0);
  z[2 * n + 1] = fmaf(eps2[2 * n + 1], expf(0.5f * lv1), mu1);
}

// ---------------- Decoder EdgeConv via MFMA ----------------
__global__ __launch_bounds__(256) void dec_bucket(
    const float2* __restrict__ z, const unsigned* __restrict__ payload,
    const unsigned* __restrict__ start, const float* __restrict__ db1,
    const float* __restrict__ db2, const float* __restrict__ db3,
    const h2f16* __restrict__ wpk, float4* __restrict__ osum) {
  __shared__ float aO0[NB], aO1[NB], aO2[NB], aO3[NB];
  __shared__ float2 zt[NB];
  int k = blockIdx.x, node0 = k * NB;
  int tid = threadIdx.x, w = tid >> 6, lane = tid & 63;
  int q = lane >> 4, c = lane & 15;
  if (tid < NB) {
    int n = node0 + tid;
    aO0[tid] = 0; aO1[tid] = 0; aO2[tid] = 0; aO3[tid] = 0;
    zt[tid] = z[n < N_NODES ? n : 0];
  }
  __syncthreads();
  const u32x4* a2b = (const u32x4*)(wpk + PK_DEC_A2);
  f16x8 A0 = __builtin_bit_cast(f16x8, a2b[lane]);
  f16x8 A1 = __builtin_bit_cast(f16x8, a2b[64 + lane]);
  h2f16 w1d[16];
#pragma unroll
  for (int i = 0; i < 16; ++i) w1d[i] = wpk[PK_DEC_W1 + q * 16 + i];
  h2f16 hw[16];
#pragma unroll
  for (int i = 0; i < 16; ++i) hw[i] = wpk[PK_DEC_H + q * 16 + i];
  float db1v[8];
#pragma unroll
  for (int j = 0; j < 8; ++j) db1v[j] = db1[q * 8 + j];
  float d2a[4], d2b[4];
#pragma unroll
  for (int r = 0; r < 4; ++r) {
    d2a[r] = db2[4 * q + r];
    d2b[r] = db2[16 + 4 * q + r];
  }
  float b3_0 = db3[0], b3_1 = db3[1], b3_2 = db3[2], b3_3 = db3[3];
  unsigned s0 = start[k], e1 = start[k + 1];
  for (unsigned ebase = s0 + (unsigned)w * 16; ebase < e1; ebase += 64) {
    unsigned e = ebase + (unsigned)c;
    unsigned pe = (e < e1) ? e : (e1 - 1);
    unsigned p = payload[pe];
    int si = (int)(p & 0x1FFFFu);
    si = (si < N_NODES) ? si : 0;
    int lti = (int)(p >> 17);
    float2 zj = z[si];
    float2 zi = zt[lti];
    h2f16 f0 = pk(zi.x, zi.y);
    h2f16 f1 = pk(zj.x - zi.x, zj.y - zi.y);
    float r[8];
#pragma unroll
    for (int j = 0; j < 8; ++j) {
      float u = db1v[j];
      u = fdot2(f0, w1d[2 * j + 0], u);
      u = fdot2(f1, w1d[2 * j + 1], u);
      r[j] = fmaxf(u, 0.0f);
    }
    u32x4 bu;
    bu[0] = h2u(pk(r[0], r[1]));
    bu[1] = h2u(pk(r[2], r[3]));
    bu[2] = h2u(pk(r[4], r[5]));
    bu[3] = h2u(pk(r[6], r[7]));
    f16x8 B = __builtin_bit_cast(f16x8, bu);
    f32x4 C0 = {0.f, 0.f, 0.f, 0.f}, C1 = {0.f, 0.f, 0.f, 0.f};
    C0 = mfma16(A0, B, C0);
    C1 = mfma16(A1, B, C1);
    float o0 = 0, o1 = 0, o2 = 0, o3 = 0;
#pragma unroll
    for (int rr = 0; rr < 4; ++rr) {
      float d0 = fmaxf(C0[rr] + d2a[rr], 0.0f);
      float d1 = fmaxf(C1[rr] + d2b[rr], 0.0f);
      h2f16 hh = pk(d0, d1);
      o0 = fdot2(hh, hw[4 * rr + 0], o0);
      o1 = fdot2(hh, hw[4 * rr + 1], o1);
      o2 = fdot2(hh, hw[4 * rr + 2], o2);
      o3 = fdot2(hh, hw[4 * rr + 3], o3);
    }
    o0 += __shfl_xor(o0, 16); o0 += __shfl_xor(o0, 32);
    o1 += __shfl_xor(o1, 16); o1 += __shfl_xor(o1, 32);
    o2 += __shfl_xor(o2, 16); o2 += __shfl_xor(o2, 32);
    o3 += __shfl_xor(o3, 16); o3 += __shfl_xor(o3, 32);
    if (lane < 16 && e < e1) {
      atomicAdd(&aO0[lti], o0 + b3_0);
      atomicAdd(&aO1[lti], o1 + b3_1);
      atomicAdd(&aO2[lti], o2 + b3_2);
      atomicAdd(&aO3[lti], o3 + b3_3);
    }
  }
  __syncthreads();
  if (tid < NB) {
    int n = node0 + tid;
    if (n < N_NODES)
      osum[n] = make_float4(aO0[tid], aO1[tid], aO2[tid], aO3[tid]);
  }
}

__global__ __launch_bounds__(256) void node_final(float* __restrict__ osum,
                                                  const float* __restrict__ cnt) {
  int n = blockIdx.x * 256 + threadIdx.x;
  if (n >= N_NODES) return;
  float inv = 1.0f / fmaxf(cnt[n], 1.0f);
  float4* o4 = (float4*)osum;
  float4 v = o4[n];
  v.x *= inv; v.y *= inv; v.z *= inv; v.w *= inv;
  o4[n] = v;
}

// ---------------- fallback (device-scope atomics, fp32, round-1 proven) ----
__device__ __forceinline__ void atomAddF(float* p, float v) {
  unsafeAtomicAdd(p, v);
}

__global__ __launch_bounds__(256) void enc_edge_fb(
    const float4* __restrict__ x, const int* __restrict__ esrc,
    const int* __restrict__ etgt, const float* __restrict__ ab,
    const float* __restrict__ eW1, const float* __restrict__ eb1,
    const float* __restrict__ eW2, const float* __restrict__ eb2,
    const float* __restrict__ mW, const float* __restrict__ vW,
    float* __restrict__ msum, float* __restrict__ vsum,
    float* __restrict__ cnt) {
  int e = blockIdx.x * 256 + threadIdx.x;
  if (e >= N_EDGES) return;
  int si = esrc[e], ti = etgt[e];
  float4 xi = x[ti];
  float4 xj = x[si];
  float a0 = ab[0], a1 = ab[1], a2 = ab[2], a3 = ab[3];
  float b0 = ab[4], b1 = ab[5], b2 = ab[6], b3 = ab[7];
  float feat[8];
  feat[0] = fmaf(a0, xi.x, b0);
  feat[1] = fmaf(a1, xi.y, b1);
  feat[2] = fmaf(a2, xi.z, b2);
  feat[3] = fmaf(a3, xi.w, b3);
  feat[4] = a0 * (xj.x - xi.x);
  feat[5] = a1 * (xj.y - xi.y);
  feat[6] = a2 * (xj.z - xi.z);
  feat[7] = a3 * (xj.w - xi.w);
  float h1[32];
#pragma unroll 8
  for (int j = 0; j < 32; ++j) {
    float acc = eb1[j];
#pragma unroll
    for (int kk = 0; kk < 8; ++kk) acc = fmaf(feat[kk], eW1[kk * 32 + j], acc);
    h1[j] = fmaxf(acc, 0.0f);
  }
  float m0 = 0, m1 = 0, v0 = 0, v1 = 0;
#pragma unroll 4
  for (int j = 0; j < 32; ++j) {
    float acc = eb2[j];
#pragma unroll
    for (int kk = 0; kk < 32; ++kk) acc = fmaf(h1[kk], eW2[kk * 32 + j], acc);
    float h2 = fmaxf(acc, 0.0f);
    m0 = fmaf(h2, mW[j * 2 + 0], m0);
    m1 = fmaf(h2, mW[j * 2 + 1], m1);
    v0 = fmaf(h2, vW[j * 2 + 0], v0);
    v1 = fmaf(h2, vW[j * 2 + 1], v1);
  }
  atomAddF(&msum[ti * 2 + 0], m0);
  atomAddF(&msum[ti * 2 + 1], m1);
  atomAddF(&vsum[ti * 2 + 0], v0);
  atomAddF(&vsum[ti * 2 + 1], v1);
  atomAddF(&cnt[ti], 1.0f);
}

__global__ __launch_bounds__(256) void dec_edge_fb(
    const float2* __restrict__ z, const int* __restrict__ esrc,
    const int* __restrict__ etgt, const float* __restrict__ dW1,
    const float* __restrict__ db1, const float* __restrict__ dW2,
    const float* __restrict__ db2, const float* __restrict__ dW3,
    const float* __restrict__ db3, float* __restrict__ osum) {
  int e = blockIdx.x * 256 + threadIdx.x;
  if (e >= N_EDGES) return;
  int si = esrc[e], ti = etgt[e];
  float2 zi = z[ti], zj = z[si];
  float f0 = zi.x, f1 = zi.y, f2 = zj.x - zi.x, f3 = zj.y - zi.y;
  float h1[32];
#pragma unroll 8
  for (int j = 0; j < 32; ++j) {
    float acc = db1[j];
    acc = fmaf(f0, dW1[0 * 32 + j], acc);
    acc = fmaf(f1, dW1[1 * 32 + j], acc);
    acc = fmaf(f2, dW1[2 * 32 + j], acc);
    acc = fmaf(f3, dW1[3 * 32 + j], acc);
    h1[j] = fmaxf(acc, 0.0f);
  }
  float o0 = db3[0], o1 = db3[1], o2 = db3[2], o3 = db3[3];
#pragma unroll 4
  for (int j = 0; j < 32; ++j) {
    float acc = db2[j];
#pragma unroll
    for (int kk = 0; kk < 32; ++kk) acc = fmaf(h1[kk], dW2[kk * 32 + j], acc);
    float h2 = fmaxf(acc, 0.0f);
    o0 = fmaf(h2, dW3[j * 4 + 0], o0);
    o1 = fmaf(h2, dW3[j * 4 + 1], o1);
    o2 = fmaf(h2, dW3[j * 4 + 2], o2);
    o3 = fmaf(h2, dW3[j * 4 + 3], o3);
  }
  atomAddF(&osum[4 * ti + 0], o0);
  atomAddF(&osum[4 * ti + 1], o1);
  atomAddF(&osum[4 * ti + 2], o2);
  atomAddF(&osum[4 * ti + 3], o3);
}

extern "C" void kernel_launch(void* const* d_in, const int* in_sizes, int n_in,
                              void* d_out, int out_size, void* d_ws,
                              size_t ws_size, hipStream_t stream) {
  const float* x = (const float*)d_in[0];
  const int* ei = (const int*)d_in[1];
  const float* eps = (const float*)d_in[2];
  const float* bng = (const float*)d_in[3];
  const float* bnb = (const float*)d_in[4];
  const float* eW1 = (const float*)d_in[5];
  const float* eb1 = (const float*)d_in[6];
  const float* eW2 = (const float*)d_in[7];
  const float* eb2 = (const float*)d_in[8];
  const float* mW = (const float*)d_in[9];
  const float* mb = (const float*)d_in[10];
  const float* vW = (const float*)d_in[11];
  const float* vb = (const float*)d_in[12];
  const float* dW1 = (const float*)d_in[13];
  const float* db1 = (const float*)d_in[14];
  const float* dW2 = (const float*)d_in[15];
  const float* db2 = (const float*)d_in[16];
  const float* dW3 = (const float*)d_in[17];
  const float* db3 = (const float*)d_in[18];

  float* out = (float*)d_out;  // [N,4] out | [N,2] mu | [N,2] logvar
  const size_t N = N_NODES;
  float* msum = out + 4 * N;
  float* vsum = out + 6 * N;

  float* wsf = (float*)d_ws;
  float* bns = wsf;                          // 8
  float* ab = wsf + 8;                       // 8
  float* z = wsf + 16;                       // 2N
  float* cnt = wsf + 16 + 2 * N;             // N
  unsigned* start = (unsigned*)(wsf + 16 + 3 * N);      // NBUCK+1
  unsigned* hist = start + (NBUCK + 1);                 // NSLICE*NBUCK
  unsigned* payload = hist + (size_t)NSLICE * NBUCK;    // N_EDGES
  h2f16* wpk = (h2f16*)(payload + N_EDGES);             // PK_TOTAL
  const size_t REQ = (16 + 3 * N) * sizeof(float) +
                     ((size_t)(NBUCK + 1) + (size_t)NSLICE * NBUCK + N_EDGES +
                      PK_TOTAL) *
                         sizeof(unsigned);

  if (ws_size >= REQ) {
    (void)hipMemsetAsync(bns, 0, 8 * sizeof(float), stream);
    pack_weights<<<1, 256, 0, stream>>>(eW1, eW2, mW, vW, dW1, dW2, dW3, wpk);
    bn_reduce<<<256, 256, 0, stream>>>((const float4*)x, bns);
    bn_final<<<1, 64, 0, stream>>>(bns, bng, bnb, ab);
    edge_hist<<<NSLICE, 256, 0, stream>>>(ei + N_EDGES, hist);
    bucket_tot<<<(NBUCK + 255) / 256, 256, 0, stream>>>(hist, payload);
    bucket_start<<<1, 1024, 0, stream>>>(payload, start);
    bucket_bases<<<(NBUCK + 3) / 4, 256, 0, stream>>>(hist, start);
    edge_place<<<NSLICE, 256, 0, stream>>>(ei, ei + N_EDGES, hist, start,
                                           payload);
    enc_bucket<<<NBUCK, 256, 0, stream>>>((const float4*)x, payload, start, ab,
                                          eb1, eb2, wpk, (float2*)msum,
                                          (float2*)vsum, cnt);
    node_mid<<<NBLK_NODE, 256, 0, stream>>>(msum, vsum, cnt, eps, mb, vb, z);
    dec_bucket<<<NBUCK, 256, 0, stream>>>((const float2*)z, payload, start, db1,
                                          db2, db3, wpk, (float4*)out);
    node_final<<<NBLK_NODE, 256, 0, stream>>>(out, cnt);
  } else {
    float* cntf = wsf + 16;       // N
    float* zf = wsf + 16 + N;     // 2N
    (void)hipMemsetAsync(d_out, 0, 8 * N * sizeof(float), stream);
    (void)hipMemsetAsync(d_ws, 0, (16 + N) * sizeof(float), stream);
    bn_reduce<<<256, 256, 0, stream>>>((const float4*)x, bns);
    bn_final<<<1, 64, 0, stream>>>(bns, bng, bnb, ab);
    enc_edge_fb<<<NBLK_EDGE, 256, 0, stream>>>((const float4*)x, ei,
                                               ei + N_EDGES, ab, eW1, eb1, eW2,
                                               eb2, mW, vW, msum, vsum, cntf);
    node_mid<<<NBLK_NODE, 256, 0, stream>>>(msum, vsum, cntf, eps, mb, vb, zf);
    dec_edge_fb<<<NBLK_EDGE, 256, 0, stream>>>((const float2*)zf, ei,
                                               ei + N_EDGES, dW1, db1, dW2, db2,
                                               dW3, db3, out);
    node_final<<<NBLK_NODE, 256, 0, stream>>>(out, cntf);
  }
}

// Round 8
// 404.795 us; speedup vs baseline: 1.0359x; 1.0359x over previous
//
#include <hip/hip_runtime.h>
#include <math.h>

#define N_NODES 100000
#define N_EDGES 3200000
#define NBLK_EDGE ((N_EDGES + 255) / 256)
#define NBLK_NODE ((N_NODES + 255) / 256)

#define NB 64                                // nodes per bucket
#define NBUCK ((N_NODES + NB - 1) / NB)      // 1563
#define NSLICE 256
#define SLICE (N_EDGES / NSLICE)             // 12500 exact
#define P2 2048                              // pow2 >= NBUCK for the scan

typedef _Float16 h2f16 __attribute__((ext_vector_type(2)));
typedef __fp16 f16x8 __attribute__((ext_vector_type(8)));   // MFMA operand type
typedef float f32x4 __attribute__((ext_vector_type(4)));
typedef unsigned u32x4 __attribute__((ext_vector_type(4)));

// packed-weight table offsets (h2f16 units)
#define PK_ENC_A2 0     // 2 tiles x 64 lanes x 4 pairs (W2^T A-fragments)
#define PK_DEC_A2 512
#define PK_ENC_W1 1024  // [q][j][kp] 4*8*4
#define PK_DEC_W1 1152  // [q][j][kp] 4*8*2
#define PK_ENC_H 1216   // [q][r][head] pairs (out 4q+r, 16+4q+r)
#define PK_DEC_H 1280
#define PK_TOTAL 1344

__device__ __forceinline__ h2f16 mkh2(float a, float b) {
  h2f16 h;
  h.x = (_Float16)a;
  h.y = (_Float16)b;
  return h;
}
__device__ __forceinline__ float fdot2(h2f16 a, h2f16 b, float c) {
  return __builtin_amdgcn_fdot2(a, b, c, false);
}
__device__ __forceinline__ h2f16 pk(float a, float b) {
  auto r = __builtin_amdgcn_cvt_pkrtz(a, b);  // v_cvt_pkrtz_f16_f32
  return __builtin_bit_cast(h2f16, r);
}
__device__ __forceinline__ unsigned h2u(h2f16 h) {
  return __builtin_bit_cast(unsigned, h);
}
__device__ __forceinline__ f32x4 mfma16(f16x8 a, f16x8 b, f32x4 c) {
  return __builtin_amdgcn_mfma_f32_16x16x32_f16(a, b, c, 0, 0, 0);
}

// ---------------- pack weights into MFMA-fragment-ready tables ----------------
__global__ __launch_bounds__(256) void pack_weights(
    const float* __restrict__ eW1, const float* __restrict__ eW2,
    const float* __restrict__ mW, const float* __restrict__ vW,
    const float* __restrict__ dW1, const float* __restrict__ dW2,
    const float* __restrict__ dW3, h2f16* __restrict__ wpk) {
  int t = threadIdx.x;
  for (int i = t; i < 512; i += 256) {
    int tl = i >> 8, rest = i & 255, lane = rest >> 2, p = rest & 3;
    int q = lane >> 4, c = lane & 15;
    int k0 = q * 8 + 2 * p, out = 16 * tl + c;
    wpk[PK_ENC_A2 + i] = mkh2(eW2[k0 * 32 + out], eW2[(k0 + 1) * 32 + out]);
    wpk[PK_DEC_A2 + i] = mkh2(dW2[k0 * 32 + out], dW2[(k0 + 1) * 32 + out]);
  }
  for (int i = t; i < 128; i += 256) {
    int q = i >> 5, j = (i >> 2) & 7, kp = i & 3;
    wpk[PK_ENC_W1 + i] =
        mkh2(eW1[(2 * kp) * 32 + q * 8 + j], eW1[(2 * kp + 1) * 32 + q * 8 + j]);
  }
  for (int i = t; i < 64; i += 256) {
    int q = i >> 4, j = (i >> 1) & 7, kp = i & 1;
    wpk[PK_DEC_W1 + i] =
        mkh2(dW1[(2 * kp) * 32 + q * 8 + j], dW1[(2 * kp + 1) * 32 + q * 8 + j]);
  }
  for (int i = t; i < 64; i += 256) {
    int q = i >> 4, r = (i >> 2) & 3, h = i & 3;
    int o0 = 4 * q + r, o1 = 16 + 4 * q + r;
    float w0 = (h < 2) ? mW[o0 * 2 + h] : vW[o0 * 2 + (h - 2)];
    float w1 = (h < 2) ? mW[o1 * 2 + h] : vW[o1 * 2 + (h - 2)];
    wpk[PK_ENC_H + i] = mkh2(w0, w1);
    wpk[PK_DEC_H + i] = mkh2(dW3[o0 * 4 + h], dW3[o1 * 4 + h]);
  }
}

// ---------------- BatchNorm statistics ----------------
__global__ void bn_reduce(const float4* __restrict__ x, float* __restrict__ bns) {
  float s0 = 0, s1 = 0, s2 = 0, s3 = 0, q0 = 0, q1 = 0, q2 = 0, q3 = 0;
  for (int i = blockIdx.x * blockDim.x + threadIdx.x; i < N_NODES;
       i += gridDim.x * blockDim.x) {
    float4 v = x[i];
    s0 += v.x; s1 += v.y; s2 += v.z; s3 += v.w;
    q0 += v.x * v.x; q1 += v.y * v.y; q2 += v.z * v.z; q3 += v.w * v.w;
  }
#pragma unroll
  for (int o = 32; o; o >>= 1) {
    s0 += __shfl_down(s0, o); s1 += __shfl_down(s1, o);
    s2 += __shfl_down(s2, o); s3 += __shfl_down(s3, o);
    q0 += __shfl_down(q0, o); q1 += __shfl_down(q1, o);
    q2 += __shfl_down(q2, o); q3 += __shfl_down(q3, o);
  }
  __shared__ float red[4][8];
  int w = threadIdx.x >> 6;
  if ((threadIdx.x & 63) == 0) {
    red[w][0] = s0; red[w][1] = s1; red[w][2] = s2; red[w][3] = s3;
    red[w][4] = q0; red[w][5] = q1; red[w][6] = q2; red[w][7] = q3;
  }
  __syncthreads();
  if (threadIdx.x < 8) {
    float acc = red[0][threadIdx.x] + red[1][threadIdx.x] +
                red[2][threadIdx.x] + red[3][threadIdx.x];
    atomicAdd(&bns[threadIdx.x], acc);
  }
}

__global__ void bn_final(const float* __restrict__ bns,
                         const float* __restrict__ gamma,
                         const float* __restrict__ beta,
                         float* __restrict__ ab) {
  int d = threadIdx.x;
  if (d < 4) {
    float mean = bns[d] * (1.0f / N_NODES);
    float var = bns[4 + d] * (1.0f / N_NODES) - mean * mean;
    float a = gamma[d] * rsqrtf(var + 1e-5f);
    ab[d] = a;
    ab[4 + d] = beta[d] - mean * a;  // xn = a*x + b
  }
}

// ---------------- counting sort by target bucket (no global atomics) -------
__global__ __launch_bounds__(256) void edge_hist(const int* __restrict__ tgt,
                                                 unsigned* __restrict__ hist) {
  __shared__ unsigned h[NBUCK];
  for (int i = threadIdx.x; i < NBUCK; i += 256) h[i] = 0;
  __syncthreads();
  int e0 = blockIdx.x * SLICE;
  for (int i = threadIdx.x; i < SLICE; i += 256)
    atomicAdd(&h[((unsigned)tgt[e0 + i]) >> 6], 1u);
  __syncthreads();
  for (int i = threadIdx.x; i < NBUCK; i += 256)
    hist[(size_t)blockIdx.x * NBUCK + i] = h[i];
}

__global__ __launch_bounds__(256) void bucket_tot(const unsigned* __restrict__ hist,
                                                  unsigned* __restrict__ tot) {
  int k = blockIdx.x * 256 + threadIdx.x;
  if (k >= NBUCK) return;
  unsigned s = 0;
#pragma unroll 8
  for (int b = 0; b < NSLICE; ++b) s += hist[(size_t)b * NBUCK + k];
  tot[k] = s;
}

__global__ __launch_bounds__(1024) void bucket_start(const unsigned* __restrict__ tot,
                                                     unsigned* __restrict__ start) {
  __shared__ unsigned sa[P2], sb[P2];
  for (int k = threadIdx.x; k < P2; k += 1024)
    sa[k] = (k < NBUCK) ? tot[k] : 0u;
  __syncthreads();
  unsigned *srcp = sa, *dstp = sb;
  for (int off = 1; off < P2; off <<= 1) {
    for (int k = threadIdx.x; k < P2; k += 1024)
      dstp[k] = srcp[k] + (k >= off ? srcp[k - off] : 0u);
    __syncthreads();
    unsigned* t = srcp; srcp = dstp; dstp = t;
  }
  for (int k = threadIdx.x; k <= NBUCK; k += 1024)
    start[k] = (k == 0) ? 0u : srcp[k - 1];
}

__global__ __launch_bounds__(256) void bucket_bases(unsigned* __restrict__ hist,
                                                    const unsigned* __restrict__ start) {
  int wv = threadIdx.x >> 6, lane = threadIdx.x & 63;
  int k = blockIdx.x * 4 + wv;
  if (k >= NBUCK) return;
  unsigned v0 = hist[(size_t)(4 * lane + 0) * NBUCK + k];
  unsigned v1 = hist[(size_t)(4 * lane + 1) * NBUCK + k];
  unsigned v2 = hist[(size_t)(4 * lane + 2) * NBUCK + k];
  unsigned v3 = hist[(size_t)(4 * lane + 3) * NBUCK + k];
  unsigned p1 = v0, p2 = v0 + v1, p3 = v0 + v1 + v2;
  unsigned s = p3 + v3;
  unsigned incl = s;
#pragma unroll
  for (int off = 1; off < 64; off <<= 1) {
    unsigned t = __shfl_up(incl, off);
    incl += (lane >= off) ? t : 0u;
  }
  unsigned base = start[k] + (incl - s);
  hist[(size_t)(4 * lane + 0) * NBUCK + k] = base;
  hist[(size_t)(4 * lane + 1) * NBUCK + k] = base + p1;
  hist[(size_t)(4 * lane + 2) * NBUCK + k] = base + p2;
  hist[(size_t)(4 * lane + 3) * NBUCK + k] = base + p3;
}

__global__ __launch_bounds__(256) void edge_place(
    const int* __restrict__ src, const int* __restrict__ tgt,
    const unsigned* __restrict__ hist, const unsigned* __restrict__ start,
    unsigned* __restrict__ payload) {
  __shared__ unsigned stage[SLICE];
  __shared__ unsigned offA[NBUCK];
  __shared__ unsigned A2[NBUCK];
  int s = blockIdx.x, tid = threadIdx.x;
  for (int k = tid; k < NBUCK; k += 256) {
    unsigned gb = hist[(size_t)s * NBUCK + k];
    unsigned nb = (s == NSLICE - 1) ? start[k + 1]
                                    : hist[(size_t)(s + 1) * NBUCK + k];
    offA[k] = gb;
    A2[k] = nb - gb;
  }
  __syncthreads();
  for (int d = 1; d < NBUCK; d <<= 1) {
    unsigned tmp[7];
    int m = 0;
    for (int k = tid; k < NBUCK; k += 256, ++m)
      tmp[m] = (k >= d) ? A2[k - d] : 0u;
    __syncthreads();
    m = 0;
    for (int k = tid; k < NBUCK; k += 256, ++m) A2[k] += tmp[m];
    __syncthreads();
  }
  {
    unsigned tmp[7];
    int m = 0;
    for (int k = tid; k < NBUCK; k += 256, ++m)
      tmp[m] = (k == 0) ? 0u : A2[k - 1];
    __syncthreads();
    m = 0;
    for (int k = tid; k < NBUCK; k += 256, ++m) {
      offA[k] -= tmp[m];
      A2[k] = tmp[m];
    }
    __syncthreads();
  }
  int e0 = s * SLICE;
  for (int i = tid; i < SLICE; i += 256) {
    unsigned t = (unsigned)tgt[e0 + i];
    unsigned sr = (unsigned)src[e0 + i];
    unsigned b = t >> 6;
    unsigned lp = atomicAdd(&A2[b], 1u);
    stage[lp] = sr | ((t & 63u) << 17);
  }
  __syncthreads();
  for (int b = tid; b < NBUCK; b += 256) {
    unsigned beg = (b == 0) ? 0u : A2[b - 1];
    unsigned end = A2[b];
    unsigned go = offA[b];
    for (unsigned i = beg; i < end; ++i) payload[go + i] = stage[i];
  }
}

// ---------------- Encoder EdgeConv via MFMA, 2 blocks/bucket, 32 edges/iter -
__global__ __launch_bounds__(256) void enc_bucket(
    const float4* __restrict__ x, const unsigned* __restrict__ payload,
    const unsigned* __restrict__ start, const float* __restrict__ ab,
    const float* __restrict__ eb1, const float* __restrict__ eb2,
    const h2f16* __restrict__ wpk, float2* __restrict__ mpart,
    float2* __restrict__ vpart, float* __restrict__ cpart) {
  __shared__ float aM0[NB], aM1[NB], aV0[NB], aV1[NB], aC[NB];
  __shared__ float4 xt[NB];
  int k = blockIdx.x, node0 = k * NB, h = blockIdx.y;
  int tid = threadIdx.x, w = tid >> 6, lane = tid & 63;
  int q = lane >> 4, c = lane & 15;
  if (tid < NB) {
    int n = node0 + tid;
    aM0[tid] = 0; aM1[tid] = 0; aV0[tid] = 0; aV1[tid] = 0; aC[tid] = 0;
    xt[tid] = x[n < N_NODES ? n : 0];
  }
  __syncthreads();
  float a0 = ab[0], a1 = ab[1], a2 = ab[2], a3 = ab[3];
  float b0 = ab[4], b1 = ab[5], b2 = ab[6], b3 = ab[7];
  const u32x4* a2b = (const u32x4*)(wpk + PK_ENC_A2);
  f16x8 A0 = __builtin_bit_cast(f16x8, a2b[lane]);
  f16x8 A1 = __builtin_bit_cast(f16x8, a2b[64 + lane]);
  h2f16 w1e[32];
#pragma unroll
  for (int i = 0; i < 32; ++i) w1e[i] = wpk[PK_ENC_W1 + q * 32 + i];
  h2f16 hw[16];
#pragma unroll
  for (int i = 0; i < 16; ++i) hw[i] = wpk[PK_ENC_H + q * 16 + i];
  float eb1v[8];
#pragma unroll
  for (int j = 0; j < 8; ++j) eb1v[j] = eb1[q * 8 + j];
  float e2a[4], e2b[4];
#pragma unroll
  for (int r = 0; r < 4; ++r) {
    e2a[r] = eb2[4 * q + r];
    e2b[r] = eb2[16 + 4 * q + r];
  }
  unsigned s0v = start[k], s1v = start[k + 1];
  unsigned len = s1v - s0v, halfv = (len + 1) >> 1;
  unsigned lo = s0v + (h ? halfv : 0u);
  unsigned hi = h ? s1v : (s0v + halfv);
  for (unsigned base = lo + (unsigned)w * 32; base < hi; base += 128) {
    unsigned eA = base + (unsigned)c;
    unsigned eB = eA + 16;
    unsigned pA = payload[eA < hi ? eA : hi - 1];
    unsigned pB = payload[eB < hi ? eB : hi - 1];
    int siA = (int)(pA & 0x1FFFFu), siB = (int)(pB & 0x1FFFFu);
    int ltiA = (int)(pA >> 17), ltiB = (int)(pB >> 17);
    float4 xjA = x[siA];
    float4 xjB = x[siB];
    float4 xiA = xt[ltiA];
    float4 xiB = xt[ltiB];
    // group A
    h2f16 fA0 = pk(fmaf(a0, xiA.x, b0), fmaf(a1, xiA.y, b1));
    h2f16 fA1 = pk(fmaf(a2, xiA.z, b2), fmaf(a3, xiA.w, b3));
    h2f16 fA2 = pk(a0 * (xjA.x - xiA.x), a1 * (xjA.y - xiA.y));
    h2f16 fA3 = pk(a2 * (xjA.z - xiA.z), a3 * (xjA.w - xiA.w));
    // group B
    h2f16 fB0 = pk(fmaf(a0, xiB.x, b0), fmaf(a1, xiB.y, b1));
    h2f16 fB1 = pk(fmaf(a2, xiB.z, b2), fmaf(a3, xiB.w, b3));
    h2f16 fB2 = pk(a0 * (xjB.x - xiB.x), a1 * (xjB.y - xiB.y));
    h2f16 fB3 = pk(a2 * (xjB.z - xiB.z), a3 * (xjB.w - xiB.w));
    float rA[8], rB[8];
#pragma unroll
    for (int j = 0; j < 8; ++j) {
      float uA = eb1v[j], uB = eb1v[j];
      uA = fdot2(fA0, w1e[4 * j + 0], uA);
      uB = fdot2(fB0, w1e[4 * j + 0], uB);
      uA = fdot2(fA1, w1e[4 * j + 1], uA);
      uB = fdot2(fB1, w1e[4 * j + 1], uB);
      uA = fdot2(fA2, w1e[4 * j + 2], uA);
      uB = fdot2(fB2, w1e[4 * j + 2], uB);
      uA = fdot2(fA3, w1e[4 * j + 3], uA);
      uB = fdot2(fB3, w1e[4 * j + 3], uB);
      rA[j] = fmaxf(uA, 0.0f);
      rB[j] = fmaxf(uB, 0.0f);
    }
    u32x4 buA, buB;
    buA[0] = h2u(pk(rA[0], rA[1])); buA[1] = h2u(pk(rA[2], rA[3]));
    buA[2] = h2u(pk(rA[4], rA[5])); buA[3] = h2u(pk(rA[6], rA[7]));
    buB[0] = h2u(pk(rB[0], rB[1])); buB[1] = h2u(pk(rB[2], rB[3]));
    buB[2] = h2u(pk(rB[4], rB[5])); buB[3] = h2u(pk(rB[6], rB[7]));
    f16x8 BA = __builtin_bit_cast(f16x8, buA);
    f16x8 BB = __builtin_bit_cast(f16x8, buB);
    f32x4 zf = {0.f, 0.f, 0.f, 0.f};
    f32x4 C0A = mfma16(A0, BA, zf), C1A = mfma16(A1, BA, zf);
    f32x4 C0B = mfma16(A0, BB, zf), C1B = mfma16(A1, BB, zf);
    float m0A = 0, m1A = 0, v0A = 0, v1A = 0;
    float m0B = 0, m1B = 0, v0B = 0, v1B = 0;
#pragma unroll
    for (int rr = 0; rr < 4; ++rr) {
      h2f16 hA = pk(fmaxf(C0A[rr] + e2a[rr], 0.0f),
                    fmaxf(C1A[rr] + e2b[rr], 0.0f));
      h2f16 hB = pk(fmaxf(C0B[rr] + e2a[rr], 0.0f),
                    fmaxf(C1B[rr] + e2b[rr], 0.0f));
      m0A = fdot2(hA, hw[4 * rr + 0], m0A);
      m0B = fdot2(hB, hw[4 * rr + 0], m0B);
      m1A = fdot2(hA, hw[4 * rr + 1], m1A);
      m1B = fdot2(hB, hw[4 * rr + 1], m1B);
      v0A = fdot2(hA, hw[4 * rr + 2], v0A);
      v0B = fdot2(hB, hw[4 * rr + 2], v0B);
      v1A = fdot2(hA, hw[4 * rr + 3], v1A);
      v1B = fdot2(hB, hw[4 * rr + 3], v1B);
    }
    m0A += __shfl_xor(m0A, 16); m0A += __shfl_xor(m0A, 32);
    m1A += __shfl_xor(m1A, 16); m1A += __shfl_xor(m1A, 32);
    v0A += __shfl_xor(v0A, 16); v0A += __shfl_xor(v0A, 32);
    v1A += __shfl_xor(v1A, 16); v1A += __shfl_xor(v1A, 32);
    m0B += __shfl_xor(m0B, 16); m0B += __shfl_xor(m0B, 32);
    m1B += __shfl_xor(m1B, 16); m1B += __shfl_xor(m1B, 32);
    v0B += __shfl_xor(v0B, 16); v0B += __shfl_xor(v0B, 32);
    v1B += __shfl_xor(v1B, 16); v1B += __shfl_xor(v1B, 32);
    if (lane < 16) {
      if (eA < hi) {
        atomicAdd(&aM0[ltiA], m0A);
        atomicAdd(&aM1[ltiA], m1A);
        atomicAdd(&aV0[ltiA], v0A);
        atomicAdd(&aV1[ltiA], v1A);
        atomicAdd(&aC[ltiA], 1.0f);
      }
      if (eB < hi) {
        atomicAdd(&aM0[ltiB], m0B);
        atomicAdd(&aM1[ltiB], m1B);
        atomicAdd(&aV0[ltiB], v0B);
        atomicAdd(&aV1[ltiB], v1B);
        atomicAdd(&aC[ltiB], 1.0f);
      }
    }
  }
  __syncthreads();
  if (tid < NB) {
    int n = node0 + tid;
    if (n < N_NODES) {
      mpart[(size_t)h * N_NODES + n] = make_float2(aM0[tid], aM1[tid]);
      vpart[(size_t)h * N_NODES + n] = make_float2(aV0[tid], aV1[tid]);
      cpart[(size_t)h * N_NODES + n] = aC[tid];
    }
  }
}

// ---------------- combine halves + mean + bias + reparameterize ------------
__global__ __launch_bounds__(256) void node_mid(
    const float2* __restrict__ mpart, const float2* __restrict__ vpart,
    const float* __restrict__ cpart, const float* __restrict__ eps2,
    const float* __restrict__ mbias, const float* __restrict__ vbias,
    float* __restrict__ z, float* __restrict__ cntC,
    float2* __restrict__ muOut, float2* __restrict__ lvOut) {
  int n = blockIdx.x * 256 + threadIdx.x;
  if (n >= N_NODES) return;
  float2 ma = mpart[n], mb2 = mpart[N_NODES + n];
  float2 va = vpart[n], vb2 = vpart[N_NODES + n];
  float cc = cpart[n] + cpart[N_NODES + n];
  float inv = 1.0f / fmaxf(cc, 1.0f);
  float mu0 = fmaf(ma.x + mb2.x, inv, mbias[0]);
  float mu1 = fmaf(ma.y + mb2.y, inv, mbias[1]);
  float lv0 = fmaf(va.x + vb2.x, inv, vbias[0]);
  float lv1 = fmaf(va.y + vb2.y, inv, vbias[1]);
  cntC[n] = cc;
  muOut[n] = make_float2(mu0, mu1);
  lvOut[n] = make_float2(lv0, lv1);
  z[2 * n + 0] = fmaf(eps2[2 * n + 0], expf(0.5f * lv0), mu0);
  z[2 * n + 1] = fmaf(eps2[2 * n + 1], expf(0.5f * lv1), mu1);
}

// ---------------- Decoder EdgeConv via MFMA, 2 blocks/bucket ----------------
__global__ __launch_bounds__(256) void dec_bucket(
    const float2* __restrict__ z, const unsigned* __restrict__ payload,
    const unsigned* __restrict__ start, const float* __restrict__ db1,
    const float* __restrict__ db2, const float* __restrict__ db3,
    const h2f16* __restrict__ wpk, float4* __restrict__ opart) {
  __shared__ float aO0[NB], aO1[NB], aO2[NB], aO3[NB];
  __shared__ float2 zt[NB];
  int k = blockIdx.x, node0 = k * NB, h = blockIdx.y;
  int tid = threadIdx.x, w = tid >> 6, lane = tid & 63;
  int q = lane >> 4, c = lane & 15;
  if (tid < NB) {
    int n = node0 + tid;
    aO0[tid] = 0; aO1[tid] = 0; aO2[tid] = 0; aO3[tid] = 0;
    zt[tid] = z[n < N_NODES ? n : 0];
  }
  __syncthreads();
  const u32x4* a2b = (const u32x4*)(wpk + PK_DEC_A2);
  f16x8 A0 = __builtin_bit_cast(f16x8, a2b[lane]);
  f16x8 A1 = __builtin_bit_cast(f16x8, a2b[64 + lane]);
  h2f16 w1d[16];
#pragma unroll
  for (int i = 0; i < 16; ++i) w1d[i] = wpk[PK_DEC_W1 + q * 16 + i];
  h2f16 hw[16];
#pragma unroll
  for (int i = 0; i < 16; ++i) hw[i] = wpk[PK_DEC_H + q * 16 + i];
  float db1v[8];
#pragma unroll
  for (int j = 0; j < 8; ++j) db1v[j] = db1[q * 8 + j];
  float d2a[4], d2b[4];
#pragma unroll
  for (int r = 0; r < 4; ++r) {
    d2a[r] = db2[4 * q + r];
    d2b[r] = db2[16 + 4 * q + r];
  }
  float b3_0 = db3[0], b3_1 = db3[1], b3_2 = db3[2], b3_3 = db3[3];
  unsigned s0v = start[k], s1v = start[k + 1];
  unsigned len = s1v - s0v, halfv = (len + 1) >> 1;
  unsigned lo = s0v + (h ? halfv : 0u);
  unsigned hi = h ? s1v : (s0v + halfv);
  for (unsigned base = lo + (unsigned)w * 32; base < hi; base += 128) {
    unsigned eA = base + (unsigned)c;
    unsigned eB = eA + 16;
    unsigned pA = payload[eA < hi ? eA : hi - 1];
    unsigned pB = payload[eB < hi ? eB : hi - 1];
    int siA = (int)(pA & 0x1FFFFu), siB = (int)(pB & 0x1FFFFu);
    int ltiA = (int)(pA >> 17), ltiB = (int)(pB >> 17);
    float2 zjA = z[siA];
    float2 zjB = z[siB];
    float2 ziA = zt[ltiA];
    float2 ziB = zt[ltiB];
    h2f16 fA0 = pk(ziA.x, ziA.y);
    h2f16 fA1 = pk(zjA.x - ziA.x, zjA.y - ziA.y);
    h2f16 fB0 = pk(ziB.x, ziB.y);
    h2f16 fB1 = pk(zjB.x - ziB.x, zjB.y - ziB.y);
    float rA[8], rB[8];
#pragma unroll
    for (int j = 0; j < 8; ++j) {
      float uA = db1v[j], uB = db1v[j];
      uA = fdot2(fA0, w1d[2 * j + 0], uA);
      uB = fdot2(fB0, w1d[2 * j + 0], uB);
      uA = fdot2(fA1, w1d[2 * j + 1], uA);
      uB = fdot2(fB1, w1d[2 * j + 1], uB);
      rA[j] = fmaxf(uA, 0.0f);
      rB[j] = fmaxf(uB, 0.0f);
    }
    u32x4 buA, buB;
    buA[0] = h2u(pk(rA[0], rA[1])); buA[1] = h2u(pk(rA[2], rA[3]));
    buA[2] = h2u(pk(rA[4], rA[5])); buA[3] = h2u(pk(rA[6], rA[7]));
    buB[0] = h2u(pk(rB[0], rB[1])); buB[1] = h2u(pk(rB[2], rB[3]));
    buB[2] = h2u(pk(rB[4], rB[5])); buB[3] = h2u(pk(rB[6], rB[7]));
    f16x8 BA = __builtin_bit_cast(f16x8, buA);
    f16x8 BB = __builtin_bit_cast(f16x8, buB);
    f32x4 zf = {0.f, 0.f, 0.f, 0.f};
    f32x4 C0A = mfma16(A0, BA, zf), C1A = mfma16(A1, BA, zf);
    f32x4 C0B = mfma16(A0, BB, zf), C1B = mfma16(A1, BB, zf);
    float o0A = 0, o1A = 0, o2A = 0, o3A = 0;
    float o0B = 0, o1B = 0, o2B = 0, o3B = 0;
#pragma unroll
    for (int rr = 0; rr < 4; ++rr) {
      h2f16 hA = pk(fmaxf(C0A[rr] + d2a[rr], 0.0f),
                    fmaxf(C1A[rr] + d2b[rr], 0.0f));
      h2f16 hB = pk(fmaxf(C0B[rr] + d2a[rr], 0.0f),
                    fmaxf(C1B[rr] + d2b[rr], 0.0f));
      o0A = fdot2(hA, hw[4 * rr + 0], o0A);
      o0B = fdot2(hB, hw[4 * rr + 0], o0B);
      o1A = fdot2(hA, hw[4 * rr + 1], o1A);
      o1B = fdot2(hB, hw[4 * rr + 1], o1B);
      o2A = fdot2(hA, hw[4 * rr + 2], o2A);
      o2B = fdot2(hB, hw[4 * rr + 2], o2B);
      o3A = fdot2(hA, hw[4 * rr + 3], o3A);
      o3B = fdot2(hB, hw[4 * rr + 3], o3B);
    }
    o0A += __shfl_xor(o0A, 16); o0A += __shfl_xor(o0A, 32);
    o1A += __shfl_xor(o1A, 16); o1A += __shfl_xor(o1A, 32);
    o2A += __shfl_xor(o2A, 16); o2A += __shfl_xor(o2A, 32);
    o3A += __shfl_xor(o3A, 16); o3A += __shfl_xor(o3A, 32);
    o0B += __shfl_xor(o0B, 16); o0B += __shfl_xor(o0B, 32);
    o1B += __shfl_xor(o1B, 16); o1B += __shfl_xor(o1B, 32);
    o2B += __shfl_xor(o2B, 16); o2B += __shfl_xor(o2B, 32);
    o3B += __shfl_xor(o3B, 16); o3B += __shfl_xor(o3B, 32);
    if (lane < 16) {
      if (eA < hi) {
        atomicAdd(&aO0[ltiA], o0A + b3_0);
        atomicAdd(&aO1[ltiA], o1A + b3_1);
        atomicAdd(&aO2[ltiA], o2A + b3_2);
        atomicAdd(&aO3[ltiA], o3A + b3_3);
      }
      if (eB < hi) {
        atomicAdd(&aO0[ltiB], o0B + b3_0);
        atomicAdd(&aO1[ltiB], o1B + b3_1);
        atomicAdd(&aO2[ltiB], o2B + b3_2);
        atomicAdd(&aO3[ltiB], o3B + b3_3);
      }
    }
  }
  __syncthreads();
  if (tid < NB) {
    int n = node0 + tid;
    if (n < N_NODES)
      opart[(size_t)h * N_NODES + n] =
          make_float4(aO0[tid], aO1[tid], aO2[tid], aO3[tid]);
  }
}

__global__ __launch_bounds__(256) void node_final(
    const float4* __restrict__ opart, const float* __restrict__ cntC,
    float4* __restrict__ outp) {
  int n = blockIdx.x * 256 + threadIdx.x;
  if (n >= N_NODES) return;
  float4 a = opart[n], b = opart[N_NODES + n];
  float inv = 1.0f / fmaxf(cntC[n], 1.0f);
  outp[n] = make_float4((a.x + b.x) * inv, (a.y + b.y) * inv,
                        (a.z + b.z) * inv, (a.w + b.w) * inv);
}

// ---------------- fallback (device-scope atomics, fp32, round-1 proven) ----
__device__ __forceinline__ void atomAddF(float* p, float v) {
  unsafeAtomicAdd(p, v);
}

__global__ __launch_bounds__(256) void enc_edge_fb(
    const float4* __restrict__ x, const int* __restrict__ esrc,
    const int* __restrict__ etgt, const float* __restrict__ ab,
    const float* __restrict__ eW1, const float* __restrict__ eb1,
    const float* __restrict__ eW2, const float* __restrict__ eb2,
    const float* __restrict__ mW, const float* __restrict__ vW,
    float* __restrict__ msum, float* __restrict__ vsum,
    float* __restrict__ cnt) {
  int e = blockIdx.x * 256 + threadIdx.x;
  if (e >= N_EDGES) return;
  int si = esrc[e], ti = etgt[e];
  float4 xi = x[ti];
  float4 xj = x[si];
  float a0 = ab[0], a1 = ab[1], a2 = ab[2], a3 = ab[3];
  float b0 = ab[4], b1 = ab[5], b2 = ab[6], b3 = ab[7];
  float feat[8];
  feat[0] = fmaf(a0, xi.x, b0);
  feat[1] = fmaf(a1, xi.y, b1);
  feat[2] = fmaf(a2, xi.z, b2);
  feat[3] = fmaf(a3, xi.w, b3);
  feat[4] = a0 * (xj.x - xi.x);
  feat[5] = a1 * (xj.y - xi.y);
  feat[6] = a2 * (xj.z - xi.z);
  feat[7] = a3 * (xj.w - xi.w);
  float h1[32];
#pragma unroll 8
  for (int j = 0; j < 32; ++j) {
    float acc = eb1[j];
#pragma unroll
    for (int kk = 0; kk < 8; ++kk) acc = fmaf(feat[kk], eW1[kk * 32 + j], acc);
    h1[j] = fmaxf(acc, 0.0f);
  }
  float m0 = 0, m1 = 0, v0 = 0, v1 = 0;
#pragma unroll 4
  for (int j = 0; j < 32; ++j) {
    float acc = eb2[j];
#pragma unroll
    for (int kk = 0; kk < 32; ++kk) acc = fmaf(h1[kk], eW2[kk * 32 + j], acc);
    float h2 = fmaxf(acc, 0.0f);
    m0 = fmaf(h2, mW[j * 2 + 0], m0);
    m1 = fmaf(h2, mW[j * 2 + 1], m1);
    v0 = fmaf(h2, vW[j * 2 + 0], v0);
    v1 = fmaf(h2, vW[j * 2 + 1], v1);
  }
  atomAddF(&msum[ti * 2 + 0], m0);
  atomAddF(&msum[ti * 2 + 1], m1);
  atomAddF(&vsum[ti * 2 + 0], v0);
  atomAddF(&vsum[ti * 2 + 1], v1);
  atomAddF(&cnt[ti], 1.0f);
}

__global__ __launch_bounds__(256) void dec_edge_fb(
    const float2* __restrict__ z, const int* __restrict__ esrc,
    const int* __restrict__ etgt, const float* __restrict__ dW1,
    const float* __restrict__ db1, const float* __restrict__ dW2,
    const float* __restrict__ db2, const float* __restrict__ dW3,
    const float* __restrict__ db3, float* __restrict__ osum) {
  int e = blockIdx.x * 256 + threadIdx.x;
  if (e >= N_EDGES) return;
  int si = esrc[e], ti = etgt[e];
  float2 zi = z[ti], zj = z[si];
  float f0 = zi.x, f1 = zi.y, f2 = zj.x - zi.x, f3 = zj.y - zi.y;
  float h1[32];
#pragma unroll 8
  for (int j = 0; j < 32; ++j) {
    float acc = db1[j];
    acc = fmaf(f0, dW1[0 * 32 + j], acc);
    acc = fmaf(f1, dW1[1 * 32 + j], acc);
    acc = fmaf(f2, dW1[2 * 32 + j], acc);
    acc = fmaf(f3, dW1[3 * 32 + j], acc);
    h1[j] = fmaxf(acc, 0.0f);
  }
  float o0 = db3[0], o1 = db3[1], o2 = db3[2], o3 = db3[3];
#pragma unroll 4
  for (int j = 0; j < 32; ++j) {
    float acc = db2[j];
#pragma unroll
    for (int kk = 0; kk < 32; ++kk) acc = fmaf(h1[kk], dW2[kk * 32 + j], acc);
    float h2 = fmaxf(acc, 0.0f);
    o0 = fmaf(h2, dW3[j * 4 + 0], o0);
    o1 = fmaf(h2, dW3[j * 4 + 1], o1);
    o2 = fmaf(h2, dW3[j * 4 + 2], o2);
    o3 = fmaf(h2, dW3[j * 4 + 3], o3);
  }
  atomAddF(&osum[4 * ti + 0], o0);
  atomAddF(&osum[4 * ti + 1], o1);
  atomAddF(&osum[4 * ti + 2], o2);
  atomAddF(&osum[4 * ti + 3], o3);
}

__global__ __launch_bounds__(256) void node_mid_fb(
    float* __restrict__ msum, float* __restrict__ vsum,
    const float* __restrict__ cnt, const float* __restrict__ eps2,
    const float* __restrict__ mb, const float* __restrict__ vb,
    float* __restrict__ z) {
  int n = blockIdx.x * 256 + threadIdx.x;
  if (n >= N_NODES) return;
  float inv = 1.0f / fmaxf(cnt[n], 1.0f);
  float mu0 = fmaf(msum[2 * n + 0], inv, mb[0]);
  float mu1 = fmaf(msum[2 * n + 1], inv, mb[1]);
  float lv0 = fmaf(vsum[2 * n + 0], inv, vb[0]);
  float lv1 = fmaf(vsum[2 * n + 1], inv, vb[1]);
  msum[2 * n + 0] = mu0;
  msum[2 * n + 1] = mu1;
  vsum[2 * n + 0] = lv0;
  vsum[2 * n + 1] = lv1;
  z[2 * n + 0] = fmaf(eps2[2 * n + 0], expf(0.5f * lv0), mu0);
  z[2 * n + 1] = fmaf(eps2[2 * n + 1], expf(0.5f * lv1), mu1);
}

__global__ __launch_bounds__(256) void node_final_fb(
    float* __restrict__ osum, const float* __restrict__ cnt) {
  int n = blockIdx.x * 256 + threadIdx.x;
  if (n >= N_NODES) return;
  float inv = 1.0f / fmaxf(cnt[n], 1.0f);
  float4* o4 = (float4*)osum;
  float4 v = o4[n];
  v.x *= inv; v.y *= inv; v.z *= inv; v.w *= inv;
  o4[n] = v;
}

extern "C" void kernel_launch(void* const* d_in, const int* in_sizes, int n_in,
                              void* d_out, int out_size, void* d_ws,
                              size_t ws_size, hipStream_t stream) {
  const float* x = (const float*)d_in[0];
  const int* ei = (const int*)d_in[1];
  const float* eps = (const float*)d_in[2];
  const float* bng = (const float*)d_in[3];
  const float* bnb = (const float*)d_in[4];
  const float* eW1 = (const float*)d_in[5];
  const float* eb1 = (const float*)d_in[6];
  const float* eW2 = (const float*)d_in[7];
  const float* eb2 = (const float*)d_in[8];
  const float* mW = (const float*)d_in[9];
  const float* mb = (const float*)d_in[10];
  const float* vW = (const float*)d_in[11];
  const float* vb = (const float*)d_in[12];
  const float* dW1 = (const float*)d_in[13];
  const float* db1 = (const float*)d_in[14];
  const float* dW2 = (const float*)d_in[15];
  const float* db2 = (const float*)d_in[16];
  const float* dW3 = (const float*)d_in[17];
  const float* db3 = (const float*)d_in[18];

  float* out = (float*)d_out;  // [N,4] out | [N,2] mu | [N,2] logvar
  const size_t N = N_NODES;

  float* wsf = (float*)d_ws;
  float* bns = wsf;                          // 8
  float* ab = wsf + 8;                       // 8
  float* z = wsf + 16;                       // 2N
  float* cntC = z + 2 * N;                   // N
  float* cpart = cntC + N;                   // 2N (2 copies)
  float2* mpart = (float2*)(cpart + 2 * N);  // 2 x N float2 (4N floats)
  float2* vpart = mpart + 2 * N;             // 4N floats
  float4* opart = (float4*)((float*)vpart + 4 * N);  // 8N floats
  unsigned* start = (unsigned*)((float*)opart + 8 * N);  // NBUCK+1
  unsigned* hist = start + (NBUCK + 1);                  // NSLICE*NBUCK
  unsigned* payload = hist + (size_t)NSLICE * NBUCK;     // N_EDGES
  h2f16* wpk = (h2f16*)(payload + N_EDGES);              // PK_TOTAL
  const size_t REQ = (16 + 21 * N) * sizeof(float) +
                     ((size_t)(NBUCK + 1) + (size_t)NSLICE * NBUCK + N_EDGES +
                      PK_TOTAL) *
                         sizeof(unsigned);

  if (ws_size >= REQ) {
    (void)hipMemsetAsync(bns, 0, 8 * sizeof(float), stream);
    pack_weights<<<1, 256, 0, stream>>>(eW1, eW2, mW, vW, dW1, dW2, dW3, wpk);
    bn_reduce<<<256, 256, 0, stream>>>((const float4*)x, bns);
    bn_final<<<1, 64, 0, stream>>>(bns, bng, bnb, ab);
    edge_hist<<<NSLICE, 256, 0, stream>>>(ei + N_EDGES, hist);
    bucket_tot<<<(NBUCK + 255) / 256, 256, 0, stream>>>(hist, payload);
    bucket_start<<<1, 1024, 0, stream>>>(payload, start);
    bucket_bases<<<(NBUCK + 3) / 4, 256, 0, stream>>>(hist, start);
    edge_place<<<NSLICE, 256, 0, stream>>>(ei, ei + N_EDGES, hist, start,
                                           payload);
    dim3 gE(NBUCK, 2);
    enc_bucket<<<gE, 256, 0, stream>>>((const float4*)x, payload, start, ab,
                                       eb1, eb2, wpk, mpart, vpart, cpart);
    node_mid<<<NBLK_NODE, 256, 0, stream>>>(mpart, vpart, cpart, eps, mb, vb,
                                            z, cntC, (float2*)(out + 4 * N),
                                            (float2*)(out + 6 * N));
    dec_bucket<<<gE, 256, 0, stream>>>((const float2*)z, payload, start, db1,
                                       db2, db3, wpk, opart);
    node_final<<<NBLK_NODE, 256, 0, stream>>>(opart, cntC, (float4*)out);
  } else {
    // fallback: device-scope atomics (round-1 proven path)
    float* cntf = wsf + 16;       // N
    float* zf = wsf + 16 + N;     // 2N
    float* msum = out + 4 * N;
    float* vsum = out + 6 * N;
    (void)hipMemsetAsync(d_out, 0, 8 * N * sizeof(float), stream);
    (void)hipMemsetAsync(d_ws, 0, (16 + N) * sizeof(float), stream);
    bn_reduce<<<256, 256, 0, stream>>>((const float4*)x, bns);
    bn_final<<<1, 64, 0, stream>>>(bns, bng, bnb, ab);
    enc_edge_fb<<<NBLK_EDGE, 256, 0, stream>>>((const float4*)x, ei,
                                               ei + N_EDGES, ab, eW1, eb1, eW2,
                                               eb2, mW, vW, msum, vsum, cntf);
    node_mid_fb<<<NBLK_NODE, 256, 0, stream>>>(msum, vsum, cntf, eps, mb, vb,
                                               zf);
    dec_edge_fb<<<NBLK_EDGE, 256, 0, stream>>>((const float2*)zf, ei,
                                               ei + N_EDGES, dW1, db1, dW2, db2,
                                               dW3, db3, out);
    node_final_fb<<<NBLK_NODE, 256, 0, stream>>>(out, cntf);
  }
}